// Round 13
// baseline (1147.725 us; speedup 1.0000x reference)
//
#include <hip/hip_runtime.h>
#include <hip/hip_bf16.h>
#include <stdint.h>

// Problem constants (LSTM_36825049596199)
#define B_    64
#define T_    512
#define EMB_  128
#define H_    128
#define G4    512            // 4*H
#define M_    (B_ * T_)      // 32768 rows for the input-projection GEMM

typedef __attribute__((ext_vector_type(8))) short     short8;   // 8 bf16 MFMA frag
typedef __attribute__((ext_vector_type(4))) float     floatx4;  // MFMA acc frag
typedef __attribute__((ext_vector_type(2))) _Float16  half2v;   // packed f16 (v_dot2)

#define GLDS(g, l) __builtin_amdgcn_global_load_lds( \
    (__attribute__((address_space(1))) void*)(g),    \
    (__attribute__((address_space(3))) void*)(l), 16, 0, 0)

__device__ __forceinline__ unsigned short f2bf_bits(float f) {
  __hip_bfloat16 h = __float2bfloat16(f);
  return *reinterpret_cast<unsigned short*>(&h);
}
__device__ __forceinline__ float bf_bits2f(unsigned short u) {
  unsigned int x = ((unsigned int)u) << 16;
  return __uint_as_float(x);
}
__device__ __forceinline__ float sigm(float x) {
  return __fdividef(1.0f, 1.0f + __expf(-x));
}
__device__ __forceinline__ float tanh_fast(float x) {
  return 1.0f - __fdividef(2.0f, __expf(2.0f * x) + 1.0f);
}

__device__ __forceinline__ unsigned int pack_f16x2(float a, float b) {
  half2v h; h.x = (_Float16)a; h.y = (_Float16)b;
  return __builtin_bit_cast(unsigned int, h);
}
__device__ __forceinline__ half2v u2h2(unsigned int u) {
  return __builtin_bit_cast(half2v, u);
}

#if __has_builtin(__builtin_amdgcn_fdot2)
__device__ __forceinline__ float fdot2(half2v a, half2v b, float c) {
  return __builtin_amdgcn_fdot2(a, b, c, false);   // v_dot2_f32_f16, fp32 acc
}
#else
__device__ __forceinline__ float fdot2(half2v a, half2v b, float c) {
  return fmaf((float)a.x, (float)b.x, fmaf((float)a.y, (float)b.y, c));
}
#endif

// Quad butterfly (lanes 4k..4k+3) — two DPP stages, pure VALU.
__device__ __forceinline__ float quad_bfly_add(float x) {
  float y = x + __int_as_float(
      __builtin_amdgcn_mov_dpp(__float_as_int(x), 0xB1, 0xF, 0xF, true));
  return y + __int_as_float(
      __builtin_amdgcn_mov_dpp(__float_as_int(y), 0x4E, 0xF, 0xF, true));
}

// LDS-only barrier (precise builtins). 0xC07F: vmcnt=63, expcnt=7, lgkmcnt=0.
__device__ __forceinline__ void barrier_lds_only() {
  __builtin_amdgcn_s_waitcnt(0xC07F);
  __builtin_amdgcn_s_barrier();
}

// xg element type templated: float (precise) if workspace allows, bf16 otherwise.
__device__ __forceinline__ void  store_xg(float* p, float v)  { *p = v; }
__device__ __forceinline__ void  store_xg(unsigned short* p, float v) { *p = f2bf_bits(v); }
__device__ __forceinline__ float load_xg(const float* p)  { return *p; }
__device__ __forceinline__ float load_xg(const unsigned short* p) { return bf_bits2f(*p); }

// ---------------------------------------------------------------------------
// Embedding gather: x0[b,t,:] = bf16(emb[X[b,t],:]).
__global__ void k_gather(const int* __restrict__ X, const float* __restrict__ emb,
                         unsigned short* __restrict__ x0) {
  int i = blockIdx.x * 256 + threadIdx.x;
  int row = i >> 5, c4 = i & 31;
  float4 v = ((const float4*)emb)[(size_t)X[row] * 32 + c4];
  ushort4 o;
  o.x = f2bf_bits(v.x); o.y = f2bf_bits(v.y); o.z = f2bf_bits(v.z); o.w = f2bf_bits(v.w);
  ((ushort4*)x0)[i] = o;
}

// Per-layer prep: w_ih -> bf16, bias_sum = b_ih + b_hh.
__global__ void k_prep(const float* __restrict__ w, const float* __restrict__ bi,
                       const float* __restrict__ bh, unsigned short* __restrict__ wb,
                       float* __restrict__ bias, int nw) {
  int i = blockIdx.x * blockDim.x + threadIdx.x;
  int stride = gridDim.x * blockDim.x;
  for (int k = i; k < nw; k += stride) wb[k] = f2bf_bits(w[k]);
  for (int k = i; k < 2 * G4; k += stride) bias[k] = bi[k] + bh[k];
}

// W_hh f16-pack for the R13 4-wave / 4-way k-split / 2-units-per-lane layout:
// thread ts: lane=ts&63, w=ts>>6, p=lane&3, q=lane>>2.
// Lane covers units uA=w*32+q and uB=uA+16, k in [32p,32p+32).
// d = U*64 + g*16 + jj (U=0:A,1:B; g gate; jj k-pair) -> f16 pair (k=32p+2jj).
// wf flat index = ((dir*32 + i4)*256 + ts)*4 + qq, with d = i4*4+qq.
__global__ void k_prep_whh(const float* __restrict__ Whh, unsigned int* __restrict__ wf) {
  int i = blockIdx.x * 256 + threadIdx.x;          // [0, 65536)
  int dir = i >> 15;
  int r   = i & 0x7FFF;
  int i4  = r >> 10;         // 0..31
  int r2  = r & 0x3FF;
  int ts  = r2 >> 2;         // 0..255
  int qq  = r2 & 3;
  int d   = i4 * 4 + qq;     // 0..127
  int U   = d >> 6;
  int g   = (d >> 4) & 3;
  int jj  = d & 15;
  int lane = ts & 63, w = ts >> 6;
  int p = lane & 3, q = lane >> 2;
  int u = w * 32 + U * 16 + q;
  int k = 32 * p + 2 * jj;
  const float* wr = Whh + ((size_t)dir * G4 + g * H_ + u) * H_ + k;
  wf[i] = pack_f16x2(wr[0], wr[1]);
}

// ---------------------------------------------------------------------------
// Input-projection GEMM (NT) — unchanged (m97-style, gate-major xg columns).
template <typename XG_T>
__global__ __launch_bounds__(256, 2) void k_gemm(
    const unsigned short* __restrict__ A,   // [M_, K] bf16 row-major
    const unsigned short* __restrict__ W,   // [2][G4][K] bf16 row-major
    const float* __restrict__ bias,         // [2][G4]
    XG_T* __restrict__ xg,                  // [2][M_][G4]
    int K) {
  __shared__ unsigned short sA[128 * 32];
  __shared__ unsigned short sB[128 * 32];
  const int tid  = threadIdx.x;
  const int lane = tid & 63;
  const int wave = tid >> 6;
  const int mt = blockIdx.x, nt = blockIdx.y, dir = blockIdx.z;
  const size_t Arow0 = (size_t)mt * 128;
  const int    Ncol0 = nt * 128;
  const unsigned short* Wd = W + (size_t)dir * G4 * K;

  const int srow = tid >> 2;
  const int qlog = (tid & 3) ^ ((tid >> 4) & 3);
  auto ldsA0 = (__attribute__((address_space(3))) void*)(sA + wave * 512);
  auto ldsA1 = (__attribute__((address_space(3))) void*)(sA + 2048 + wave * 512);
  auto ldsB0 = (__attribute__((address_space(3))) void*)(sB + wave * 512);
  auto ldsB1 = (__attribute__((address_space(3))) void*)(sB + 2048 + wave * 512);

  floatx4 acc[4][4];
#pragma unroll
  for (int i = 0; i < 4; ++i)
#pragma unroll
    for (int j = 0; j < 4; ++j) acc[i][j] = (floatx4)0.0f;

  const int wrow = (wave >> 1) * 64, wcol = (wave & 1) * 64;
  const int frow = lane & 15;
  const int fq   = lane >> 4;

  for (int kt = 0; kt < K; kt += 32) {
    const unsigned short* gA0 = A  + (Arow0 + srow) * (size_t)K + kt + qlog * 8;
    const unsigned short* gB0 = Wd + (size_t)(Ncol0 + srow) * K + kt + qlog * 8;
    GLDS(gA0, ldsA0);
    GLDS(gA0 + (size_t)64 * K, ldsA1);
    GLDS(gB0, ldsB0);
    GLDS(gB0 + (size_t)64 * K, ldsB1);
    __syncthreads();

    short8 af[4], bf[4];
#pragma unroll
    for (int i = 0; i < 4; ++i) {
      int r  = wrow + 16 * i + frow;
      int rn = wcol + 16 * i + frow;
      af[i] = *(const short8*)(sA + r  * 32 + ((fq ^ ((r  >> 2) & 3)) * 8));
      bf[i] = *(const short8*)(sB + rn * 32 + ((fq ^ ((rn >> 2) & 3)) * 8));
    }
#pragma unroll
    for (int i = 0; i < 4; ++i)
#pragma unroll
      for (int j = 0; j < 4; ++j)
        acc[i][j] = __builtin_amdgcn_mfma_f32_16x16x32_bf16(af[i], bf[j], acc[i][j], 0, 0, 0);
    __syncthreads();
  }

  const int r0 = (lane >> 4) * 4;
  const int cc = lane & 15;
  XG_T* xgd = xg + (size_t)dir * M_ * G4;
#pragma unroll
  for (int j = 0; j < 4; ++j) {
    int gcol = Ncol0 + wcol + 16 * j + cc;
    float bs = bias[dir * G4 + gcol];
#pragma unroll
    for (int i = 0; i < 4; ++i) {
      size_t rowb = Arow0 + wrow + 16 * i + r0;
#pragma unroll
      for (int r = 0; r < 4; ++r)
        store_xg(&xgd[(rowb + r) * G4 + gcol], acc[i][j][r] + bs);
    }
  }
}

// ---------------------------------------------------------------------------
// Recurrent scan — R13: 4 waves (1/SIMD, R12-proven) + 4-way k-split with
// 2 units/lane. R12 step ~1470 cyc decomposes as DS ~400 (36 b128-class
// instrs/CU @ ~12cyc on the shared pipe) + fdot issue 256 + tails. This
// round halves the DS term: lane = (p=lane&3, q=lane>>2) covers units
// uA=w*32+q and uB=uA+16 with k in [32p,32p+32) -> h slice 64B = 4
// ds_read_b128 (was 8), weights still 128 f16-dwords/lane (VGPR-resident).
// 8 fdot chains (2 units x 4 gates) x 16 deep = same 128 fdot2 issue.
// Quad DPP reduce; lanes p<2 finalize unit A, p>=2 unit B (nonlin
// replication x2 not x4); p==0 writes hA/yA, p==2 writes hB/yB.
template <typename XG_T>
__global__ __attribute__((amdgpu_flat_work_group_size(256, 256),
                          amdgpu_waves_per_eu(1, 1))) void k_scan(
    const unsigned int* __restrict__ wf,  // [2][32][256][4] packed f16 pairs
    const float* __restrict__ hx0,        // [2][B_][H_] (layer base)
    const float* __restrict__ cx0,
    const XG_T* __restrict__ xg,          // [2][M_][G4] gate-major
    unsigned short* __restrict__ y)       // [B_][T_][2*H_] bf16
{
  const int b   = blockIdx.x & 63;
  const int dir = blockIdx.x >> 6;
  const int tid = threadIdx.x;
  const int lane = tid & 63;
  const int wave = tid >> 6;
  const int p  = lane & 3;        // k-slice (32 k each)
  const int q  = lane >> 2;       // unit-group within wave (0..15)
  const int uA = wave * 32 + q;
  const int uB = uA + 16;
  const int u  = (p >> 1) ? uB : uA;   // unit this lane finalizes

  __shared__ __align__(16) unsigned short h16[2][128];

  // Weights: 32 coalesced uint4 loads; d = U*64+g*16+jj -> wv[d>>2][d&3].
  uint4 wv[32];
  const uint4* wfv = (const uint4*)wf;
#pragma unroll
  for (int i = 0; i < 32; ++i) wv[i] = wfv[(dir * 32 + i) * 256 + tid];

  float c = cx0[(size_t)dir * B_ * H_ + b * H_ + u];   // c for finalized unit
  if ((p & 1) == 0) {   // p==0 writes uA, p==2 writes uB
    float h0 = hx0[(size_t)dir * B_ * H_ + b * H_ + u];
    h16[0][u] = (unsigned short)(pack_f16x2(h0, 0.0f) & 0xFFFF);
  }

  // xg (gate-major cols g*128+unit): lane folds gate p for BOTH units.
  const XG_T* xgb = xg + ((size_t)dir * M_ + (size_t)b * T_) * G4;
  const intptr_t xstep = dir ? -(intptr_t)G4 : (intptr_t)G4;
  const int oA = p * H_ + uA, oB = oA + 16;
  const XG_T* xrow0 = xgb + (dir ? (size_t)(T_ - 1) * G4 : 0);
  float xa0 = load_xg(xrow0 + oA), xb0 = load_xg(xrow0 + oB);
  float xa1 = load_xg(xrow0 + xstep + oA), xb1 = load_xg(xrow0 + xstep + oB);
  const XG_T* xld = xrow0 + 2 * xstep;

  unsigned short* yp = y + ((size_t)b * T_ + (dir ? T_ - 1 : 0)) * (2 * H_)
                         + dir * H_ + u;
  const intptr_t ystep = dir ? -(intptr_t)(2 * H_) : (intptr_t)(2 * H_);

  __syncthreads();   // init h visible (full drain fine, once)

#define WVD(d) u2h2(((const unsigned int*)&wv[(d) >> 2])[(d) & 3])

  // dot phase: h slice [32p,32p+32) k (4 b128 reads), 8 chains x16 fdot2.
  auto dots = [&](int par, float xa, float xb, float* s) {
    const uint4* hv4 = (const uint4*)&h16[par][0];
    uint4 h0v = hv4[4 * p + 0], h1v = hv4[4 * p + 1];
    uint4 h2v = hv4[4 * p + 2], h3v = hv4[4 * p + 3];
    half2v hh[16] = {
      u2h2(h0v.x), u2h2(h0v.y), u2h2(h0v.z), u2h2(h0v.w),
      u2h2(h1v.x), u2h2(h1v.y), u2h2(h1v.z), u2h2(h1v.w),
      u2h2(h2v.x), u2h2(h2v.y), u2h2(h2v.z), u2h2(h2v.w),
      u2h2(h3v.x), u2h2(h3v.y), u2h2(h3v.z), u2h2(h3v.w)};
    float A0 = 0, A1 = 0, A2 = 0, A3 = 0, B0 = 0, B1 = 0, B2 = 0, B3 = 0;
#pragma unroll
    for (int jj = 0; jj < 16; ++jj) {
      A0 = fdot2(WVD(0 * 16 + jj), hh[jj], A0);
      A1 = fdot2(WVD(1 * 16 + jj), hh[jj], A1);
      A2 = fdot2(WVD(2 * 16 + jj), hh[jj], A2);
      A3 = fdot2(WVD(3 * 16 + jj), hh[jj], A3);
      B0 = fdot2(WVD(64 + 0 * 16 + jj), hh[jj], B0);
      B1 = fdot2(WVD(64 + 1 * 16 + jj), hh[jj], B1);
      B2 = fdot2(WVD(64 + 2 * 16 + jj), hh[jj], B2);
      B3 = fdot2(WVD(64 + 3 * 16 + jj), hh[jj], B3);
    }
    // fold xg for gate p (added exactly once across the quad reduction)
    A0 += (p == 0) ? xa : 0.0f;  B0 += (p == 0) ? xb : 0.0f;
    A1 += (p == 1) ? xa : 0.0f;  B1 += (p == 1) ? xb : 0.0f;
    A2 += (p == 2) ? xa : 0.0f;  B2 += (p == 2) ? xb : 0.0f;
    A3 += (p == 3) ? xa : 0.0f;  B3 += (p == 3) ? xb : 0.0f;
    s[0] = A0; s[1] = A1; s[2] = A2; s[3] = A3;
    s[4] = B0; s[5] = B1; s[6] = B2; s[7] = B3;
  };

  auto finish = [&](int par, float* s) {
#pragma unroll
    for (int i = 0; i < 8; ++i) s[i] = quad_bfly_add(s[i]);
    // lane finalizes its unit (p<2 -> A, p>=2 -> B); replication x2
    float g0 = (p >> 1) ? s[4] : s[0];
    float g1 = (p >> 1) ? s[5] : s[1];
    float g2 = (p >> 1) ? s[6] : s[2];
    float g3 = (p >> 1) ? s[7] : s[3];
    float iv = sigm(g0), fv = sigm(g1), gv = tanh_fast(g2), ov = sigm(g3);
    c = fmaf(fv, c, iv * gv);
    float h = ov * tanh_fast(c);
    if ((p & 1) == 0) {   // p==0 writes uA, p==2 writes uB
      h16[par ^ 1][u] = (unsigned short)(pack_f16x2(h, 0.0f) & 0xFFFF);
      *yp = f2bf_bits(h);
    }
    yp += ystep;
    barrier_lds_only();
  };

  for (int t = 0; t < T_; t += 2) {
    {
      float va = xa0, vb = xb0;
      if (t + 2 < T_) { xa0 = load_xg(xld + oA); xb0 = load_xg(xld + oB); }
      else            { xa0 = 0.0f; xb0 = 0.0f; }
      xld += xstep;
      float s[8];
      dots(0, va, vb, s);
      finish(0, s);
    }
    {
      float va = xa1, vb = xb1;
      if (t + 3 < T_) { xa1 = load_xg(xld + oA); xb1 = load_xg(xld + oB); }
      else            { xa1 = 0.0f; xb1 = 0.0f; }
      xld += xstep;
      float s[8];
      dots(1, va, vb, s);
      finish(1, s);
    }
  }
#undef WVD
}

// ---------------------------------------------------------------------------
// Head: out[b] = y2[b, T-1, :] . lin_w + lin_b
__global__ void k_head(const unsigned short* __restrict__ y2, const float* __restrict__ lw,
                       const float* __restrict__ lb, float* __restrict__ out) {
  int b = blockIdx.x, l = threadIdx.x;
  const unsigned short* row = y2 + ((size_t)b * T_ + (T_ - 1)) * (2 * H_);
  float s = 0;
#pragma unroll
  for (int k = 0; k < 4; ++k) s += bf_bits2f(row[l + 64 * k]) * lw[l + 64 * k];
#pragma unroll
  for (int off = 32; off > 0; off >>= 1) s += __shfl_down(s, off);
  if (l == 0) out[b] = s + lb[0];
}

// ---------------------------------------------------------------------------
template <typename XG_T>
static inline void run_layers(const unsigned int* const* wfs,
                              const unsigned short* x0,
                              unsigned short* y0, unsigned short* y1, unsigned short* y2,
                              const unsigned short* wb0, const unsigned short* wb1,
                              const unsigned short* wb2,
                              const float* bias0, const float* bias1, const float* bias2,
                              const float* hx, const float* cx,
                              XG_T* xg, hipStream_t stream) {
  dim3 gg(M_ / 128, G4 / 128, 2);
  k_gemm<XG_T><<<gg, 256, 0, stream>>>(x0, wb0, bias0, xg, EMB_);
  k_scan<XG_T><<<128, 256, 0, stream>>>(wfs[0], hx, cx, xg, y0);
  k_gemm<XG_T><<<gg, 256, 0, stream>>>(y0, wb1, bias1, xg, 2 * H_);
  k_scan<XG_T><<<128, 256, 0, stream>>>(wfs[1], hx + 2 * B_ * H_, cx + 2 * B_ * H_, xg, y1);
  k_gemm<XG_T><<<gg, 256, 0, stream>>>(y1, wb2, bias2, xg, 2 * H_);
  k_scan<XG_T><<<128, 256, 0, stream>>>(wfs[2], hx + 4 * B_ * H_, cx + 4 * B_ * H_, xg, y2);
}

extern "C" void kernel_launch(void* const* d_in, const int* in_sizes, int n_in,
                              void* d_out, int out_size, void* d_ws, size_t ws_size,
                              hipStream_t stream) {
  const int*   X   = (const int*)d_in[0];
  const float* emb = (const float*)d_in[1];
  const float* hx  = (const float*)d_in[2];
  const float* cx  = (const float*)d_in[3];
  const float* lw  = (const float*)d_in[4];
  const float* lb  = (const float*)d_in[5];
  const float* w_ih[3] = {(const float*)d_in[6],  (const float*)d_in[10], (const float*)d_in[14]};
  const float* w_hh[3] = {(const float*)d_in[7],  (const float*)d_in[11], (const float*)d_in[15]};
  const float* b_ih[3] = {(const float*)d_in[8],  (const float*)d_in[12], (const float*)d_in[16]};
  const float* b_hh[3] = {(const float*)d_in[9],  (const float*)d_in[13], (const float*)d_in[17]};
  float* out = (float*)d_out;

  char* ws = (char*)d_ws;
  size_t off = 0;
  auto carve = [&](size_t bytes) {
    char* p = ws + off;
    off = (off + bytes + 255) & ~(size_t)255;
    return p;
  };
  unsigned short* x0  = (unsigned short*)carve((size_t)M_ * EMB_ * 2);
  unsigned short* y0  = (unsigned short*)carve((size_t)M_ * 2 * H_ * 2);
  unsigned short* y1  = (unsigned short*)carve((size_t)M_ * 2 * H_ * 2);
  unsigned short* y2  = (unsigned short*)carve((size_t)M_ * 2 * H_ * 2);
  unsigned short* wb0 = (unsigned short*)carve((size_t)2 * G4 * EMB_ * 2);
  unsigned short* wb1 = (unsigned short*)carve((size_t)2 * G4 * 2 * H_ * 2);
  unsigned short* wb2 = (unsigned short*)carve((size_t)2 * G4 * 2 * H_ * 2);
  float* bias0 = (float*)carve(2 * G4 * 4);
  float* bias1 = (float*)carve(2 * G4 * 4);
  float* bias2 = (float*)carve(2 * G4 * 4);
  unsigned int* wf0 = (unsigned int*)carve((size_t)65536 * 4);
  unsigned int* wf1 = (unsigned int*)carve((size_t)65536 * 4);
  unsigned int* wf2 = (unsigned int*)carve((size_t)65536 * 4);
  const size_t xg_f32_bytes = (size_t)2 * M_ * G4 * 4;
  const bool use_f32 = (off + xg_f32_bytes) <= ws_size;
  void* xg = carve(use_f32 ? xg_f32_bytes : xg_f32_bytes / 2);

  k_prep<<<256, 256, 0, stream>>>(w_ih[0], b_ih[0], b_hh[0], wb0, bias0, 2 * G4 * EMB_);
  k_prep<<<256, 256, 0, stream>>>(w_ih[1], b_ih[1], b_hh[1], wb1, bias1, 2 * G4 * 2 * H_);
  k_prep<<<256, 256, 0, stream>>>(w_ih[2], b_ih[2], b_hh[2], wb2, bias2, 2 * G4 * 2 * H_);
  k_prep_whh<<<256, 256, 0, stream>>>(w_hh[0], wf0);
  k_prep_whh<<<256, 256, 0, stream>>>(w_hh[1], wf1);
  k_prep_whh<<<256, 256, 0, stream>>>(w_hh[2], wf2);
  k_gather<<<(M_ * 32) / 256, 256, 0, stream>>>(X, emb, x0);

  const unsigned int* wfs[3] = {wf0, wf1, wf2};
  if (use_f32)
    run_layers<float>(wfs, x0, y0, y1, y2, wb0, wb1, wb2, bias0, bias1, bias2,
                      hx, cx, (float*)xg, stream);
  else
    run_layers<unsigned short>(wfs, x0, y0, y1, y2, wb0, wb1, wb2, bias0, bias1, bias2,
                               hx, cx, (unsigned short*)xg, stream);

  k_head<<<64, 64, 0, stream>>>(y2, lw, lb, out);
}